// Round 4
// baseline (4820.945 us; speedup 1.0000x reference)
//
#include <hip/hip_runtime.h>
#include <hip/hip_bf16.h>

namespace {

constexpr int B = 1024, T = 512, H = 60, G = 180, NTHR = 192;
constexpr int GROWS = 128;  // batch-time rows per GEMM block

__device__ __forceinline__ float sigm(float x) { return 1.f / (1.f + __expf(-x)); }
__device__ __forceinline__ float tanh_fast(float x) {
  x = fminf(fmaxf(x, -15.f), 15.f);
  const float e = __expf(-2.f * x);
  return (1.f - e) / (1.f + e);
}

__device__ __forceinline__ float ldcvt(const float* p) { return *p; }
__device__ __forceinline__ float ldcvt(const __hip_bfloat16* p) { return __bfloat162float(*p); }
__device__ __forceinline__ void stcvt(float* p, float v) { *p = v; }
__device__ __forceinline__ void stcvt(__hip_bfloat16* p, float v) { *p = __float2bfloat16(v); }

// ---------------------------------------------------------------------------
// GI GEMM: gi[tb][r] = bih[r] + sum_k x[tb][k] * Wih[r][k]
// tb = t*B+b flattened (x is [T*B][60] contiguous). Thread r holds Wih row r
// (60 floats) in registers -- same size that provably stays resident in the
// scalar rec layers. x tile staged in LDS, broadcast reads.
// ---------------------------------------------------------------------------
template <typename TS, typename TGI>
__global__ __launch_bounds__(NTHR) __attribute__((amdgpu_waves_per_eu(1, 4)))
void gi_gemm_kernel(const TS* __restrict__ x, const float* __restrict__ Wih,
                    const float* __restrict__ bih, TGI* __restrict__ gi) {
  __shared__ __align__(16) float x_sh[GROWS * H];
  const int tid = threadIdx.x;
  const size_t tb0 = (size_t)blockIdx.x * GROWS;
  const int rr = (tid < G) ? tid : 0;

  float4 W0, W1, W2, W3, W4, W5, W6, W7, W8, W9, W10, W11, W12, W13, W14;
#define LW(i) W##i = *(const float4*)&Wih[(size_t)rr * H + (i) * 4];
  LW(0) LW(1) LW(2) LW(3) LW(4) LW(5) LW(6) LW(7)
  LW(8) LW(9) LW(10) LW(11) LW(12) LW(13) LW(14)
#undef LW
  const float bi = bih[rr];

  // stage x tile (contiguous 128*60 elements)
  if constexpr (sizeof(TS) == 4) {
    const float4* s4 = (const float4*)(x + tb0 * H);
    float4* d4 = (float4*)x_sh;
    for (int i = tid; i < GROWS * H / 4; i += NTHR) d4[i] = s4[i];
  } else {
    const TS* s = x + tb0 * H;
    for (int i = tid; i < GROWS * H / 4; i += NTHR) {
      const unsigned long long u = *(const unsigned long long*)&s[i * 4];
      float4 f;
      f.x = __uint_as_float((unsigned)(u & 0xffffu) << 16);
      f.y = __uint_as_float((unsigned)((u >> 16) & 0xffffu) << 16);
      f.z = __uint_as_float((unsigned)((u >> 32) & 0xffffu) << 16);
      f.w = __uint_as_float((unsigned)((u >> 48) & 0xffffu) << 16);
      ((float4*)x_sh)[i] = f;
    }
  }
  __syncthreads();

  for (int i = 0; i < GROWS; i += 2) {
    float a0 = bi, a1 = bi;
#define GS(kk) {                                                      \
    const float4 v0 = *(const float4*)&x_sh[(i + 0) * H + 4 * (kk)];  \
    const float4 v1 = *(const float4*)&x_sh[(i + 1) * H + 4 * (kk)];  \
    a0 = fmaf(W##kk.x, v0.x, a0); a0 = fmaf(W##kk.y, v0.y, a0);       \
    a0 = fmaf(W##kk.z, v0.z, a0); a0 = fmaf(W##kk.w, v0.w, a0);       \
    a1 = fmaf(W##kk.x, v1.x, a1); a1 = fmaf(W##kk.y, v1.y, a1);       \
    a1 = fmaf(W##kk.z, v1.z, a1); a1 = fmaf(W##kk.w, v1.w, a1); }
    GS(0) GS(1) GS(2) GS(3) GS(4) GS(5) GS(6) GS(7)
    GS(8) GS(9) GS(10) GS(11) GS(12) GS(13) GS(14)
#undef GS
    if (tid < G) {
      stcvt(&gi[(tb0 + i + 0) * G + rr], a0);
      stcvt(&gi[(tb0 + i + 1) * G + rr], a1);
    }
  }
}

// ---------------------------------------------------------------------------
// Recurrent GRU layer. MODE: 0 = scalar input (F=1, whole seq in LDS),
// 1 = 60-dim input from xseq (legacy fallback; needs 120 wt floats/thread),
// 2 = precomputed gi stream (bih folded into gi; only Whh row in regs).
// ---------------------------------------------------------------------------
template <typename TS, typename TGI, int MODE, bool WRITE_YS, bool WRITE_ENC, bool WRITE_PRED>
__global__ __launch_bounds__(NTHR) __attribute__((amdgpu_waves_per_eu(1, 4)))
void gru_layer_kernel(
    const float* __restrict__ xscalar,  // [B][T] when MODE==0
    const TS* __restrict__ xseq,        // [T][B][H] when MODE==1
    const TGI* __restrict__ gi_in,      // [T][B][180] when MODE==2
    const float* __restrict__ Wih,      // [180][in] (MODE 0/1)
    const float* __restrict__ Whh,      // [180][60]
    const float* __restrict__ bih,      // (MODE 0/1)
    const float* __restrict__ bhh,
    const float* __restrict__ h_init,   // nullptr => zeros; index b*180 + j
    TS* __restrict__ ys_out,            // [T][B][H]
    float* __restrict__ enc_out,        // pre-offset by slot; index b*180 + j
    float* __restrict__ pred_out,       // [B][T]
    const float* __restrict__ lin_W,    // [60]
    const float* __restrict__ lin_b)    // [1]
{
  const int tid = threadIdx.x;
  const int b = blockIdx.x;

  __shared__ __align__(16) float h_sh[64];
  __shared__ __align__(16) float x_sh[2][64];
  __shared__ float Ar[60], Az[60], Nn[60], Hn[60];
  __shared__ float pv[64];
  __shared__ float xs_seq[T];

  const int rr = (tid < G) ? tid : 0;

  float4 Wh0, Wh1, Wh2, Wh3, Wh4, Wh5, Wh6, Wh7, Wh8, Wh9, Wh10, Wh11, Wh12, Wh13, Wh14;
#define LWH(i) Wh##i = *(const float4*)&Whh[(size_t)rr * H + (i) * 4];
  LWH(0) LWH(1) LWH(2) LWH(3) LWH(4) LWH(5) LWH(6) LWH(7)
  LWH(8) LWH(9) LWH(10) LWH(11) LWH(12) LWH(13) LWH(14)
#undef LWH

  float4 Wi0, Wi1, Wi2, Wi3, Wi4, Wi5, Wi6, Wi7, Wi8, Wi9, Wi10, Wi11, Wi12, Wi13, Wi14;
  float wih0 = 0.f;
  if constexpr (MODE == 1) {
#define LWI(i) Wi##i = *(const float4*)&Wih[(size_t)rr * H + (i) * 4];
    LWI(0) LWI(1) LWI(2) LWI(3) LWI(4) LWI(5) LWI(6) LWI(7)
    LWI(8) LWI(9) LWI(10) LWI(11) LWI(12) LWI(13) LWI(14)
#undef LWI
  } else {
    Wi0 = Wi1 = Wi2 = Wi3 = Wi4 = Wi5 = Wi6 = Wi7 = Wi8 = Wi9 = Wi10 = Wi11 = Wi12 = Wi13 = Wi14 = make_float4(0, 0, 0, 0);
    if constexpr (MODE == 0) wih0 = Wih[rr];
  }
  float bi = 0.f;
  if constexpr (MODE != 2) bi = bih[rr];
  const float bh = bhh[rr];

  float linw = 0.f, linb = 0.f;
  if constexpr (WRITE_PRED) {
    linw = lin_W[tid < H ? tid : 0];
    linb = lin_b[0];
  }

  if (tid < H) {
    h_sh[tid] = h_init ? h_init[(size_t)b * G + tid] : 0.f;
    if constexpr (MODE == 1) x_sh[0][tid] = ldcvt(&xseq[(size_t)b * H + tid]);
  }
  if constexpr (MODE == 0) {
    for (int i = tid; i < T; i += NTHR) xs_seq[i] = xscalar[(size_t)b * T + i];
  }

  // gi prefetch pipeline, 3 deep (~3 steps of latency hiding for the HBM stream)
  float gi0 = 0.f, gi1 = 0.f, gi2 = 0.f;
  if constexpr (MODE == 2) {
    if (tid < G) {
      gi0 = ldcvt(&gi_in[(size_t)(0 * B + b) * G + rr]);
      gi1 = ldcvt(&gi_in[(size_t)(1 * B + b) * G + rr]);
      gi2 = ldcvt(&gi_in[(size_t)(2 * B + b) * G + rr]);
    }
  }
  __syncthreads();

  const int g = tid / H;  // 0:r 1:z 2:n
  const int j = tid - g * H;

  for (int t = 0; t < T; ++t) {
    const int cur = t & 1, nxt = cur ^ 1;

    float xn = 0.f;   // MODE==1 next-step input
    float gin = 0.f;  // MODE==2 step t+3 gi
    if constexpr (MODE == 1) {
      if (tid < H && t + 1 < T)
        xn = ldcvt(&xseq[(size_t)(t + 1) * B * H + (size_t)b * H + tid]);
    }
    if constexpr (MODE == 2) {
      if (tid < G && t + 3 < T)
        gin = ldcvt(&gi_in[((size_t)(t + 3) * B + b) * G + rr]);
    }

    if (tid < G) {
      float a, c = bh;
      if constexpr (MODE == 2) a = gi0;
      else a = bi;
      if constexpr (MODE == 0) a = fmaf(wih0, xs_seq[t], a);

#define ACC(i)                                                              \
      {                                                                     \
        const float4 hv = *(const float4*)&h_sh[(i) * 4];                   \
        c = fmaf(Wh##i.x, hv.x, c);                                         \
        c = fmaf(Wh##i.y, hv.y, c);                                         \
        c = fmaf(Wh##i.z, hv.z, c);                                         \
        c = fmaf(Wh##i.w, hv.w, c);                                         \
        if constexpr (MODE == 1) {                                          \
          const float4 xv = *(const float4*)&x_sh[cur][(i) * 4];            \
          a = fmaf(Wi##i.x, xv.x, a);                                       \
          a = fmaf(Wi##i.y, xv.y, a);                                       \
          a = fmaf(Wi##i.z, xv.z, a);                                       \
          a = fmaf(Wi##i.w, xv.w, a);                                       \
        }                                                                   \
      }
      ACC(0) ACC(1) ACC(2) ACC(3) ACC(4) ACC(5) ACC(6) ACC(7)
      ACC(8) ACC(9) ACC(10) ACC(11) ACC(12) ACC(13) ACC(14)
#undef ACC

      if (g == 0)       Ar[j] = a + c;
      else if (g == 1)  Az[j] = a + c;
      else            { Nn[j] = a; Hn[j] = c; }
    }
    if constexpr (MODE == 2) { gi0 = gi1; gi1 = gi2; gi2 = gin; }
    __syncthreads();

    if (tid < H) {
      const float rg = sigm(Ar[tid]);
      const float zg = sigm(Az[tid]);
      const float nv = tanh_fast(fmaf(rg, Hn[tid], Nn[tid]));
      const float hnew = fmaf(zg, h_sh[tid] - nv, nv);  // (1-z)n + z h
      h_sh[tid] = hnew;
      if constexpr (WRITE_YS)
        stcvt(&ys_out[(size_t)t * B * H + (size_t)b * H + tid], hnew);
      if constexpr (MODE == 1) x_sh[nxt][tid] = xn;
      if constexpr (WRITE_PRED) pv[tid] = hnew * linw;
    }
    __syncthreads();

    if constexpr (WRITE_PRED) {
      if (tid < 64) {
        float v = (tid < H) ? pv[tid] : 0.f;
#pragma unroll
        for (int off = 32; off; off >>= 1) v += __shfl_xor(v, off);
        if (tid == 0) pred_out[(size_t)b * T + t] = v + linb;
      }
    }
  }

  if constexpr (WRITE_ENC) {
    if (tid < H) enc_out[(size_t)b * G + tid] = h_sh[tid];
  }
}

template <typename TS, typename TGI, bool USE_GI>
void launch_all(const float* inputs, const float* outputs,
                const float* eW_ih0, const float* eW_hh0, const float* eb_ih0, const float* eb_hh0,
                const float* eW_ih1, const float* eW_hh1, const float* eb_ih1, const float* eb_hh1,
                const float* eW_ih2, const float* eW_hh2, const float* eb_ih2, const float* eb_hh2,
                const float* c1_Wih, const float* c1_Whh, const float* c1_bih, const float* c1_bhh,
                const float* c2_Wih, const float* c2_Whh, const float* c2_bih, const float* c2_bhh,
                const float* c3_Wih, const float* c3_Whh, const float* c3_bih, const float* c3_bhh,
                const float* lin_W, const float* lin_b,
                float* pred, float* enc, void* d_ws, hipStream_t stream) {
  const size_t seq = (size_t)T * B * H;
  TS* ws0 = (TS*)d_ws;
  TS* ws1 = ws0 + seq;
  TGI* gi = (TGI*)(void*)(ws1 + seq);
  const dim3 grid(B), blk(NTHR), ggrid((T * B) / GROWS);

  if constexpr (USE_GI) {
    // encoder
    gru_layer_kernel<TS, TGI, 0, true, true, false><<<grid, blk, 0, stream>>>(
        inputs, nullptr, nullptr, eW_ih0, eW_hh0, eb_ih0, eb_hh0, nullptr,
        ws0, enc + 0, nullptr, nullptr, nullptr);
    gi_gemm_kernel<TS, TGI><<<ggrid, blk, 0, stream>>>(ws0, eW_ih1, eb_ih1, gi);
    gru_layer_kernel<TS, TGI, 2, true, true, false><<<grid, blk, 0, stream>>>(
        nullptr, nullptr, gi, nullptr, eW_hh1, nullptr, eb_hh1, nullptr,
        ws1, enc + 60, nullptr, nullptr, nullptr);
    gi_gemm_kernel<TS, TGI><<<ggrid, blk, 0, stream>>>(ws1, eW_ih2, eb_ih2, gi);
    gru_layer_kernel<TS, TGI, 2, false, true, false><<<grid, blk, 0, stream>>>(
        nullptr, nullptr, gi, nullptr, eW_hh2, nullptr, eb_hh2, nullptr,
        nullptr, enc + 120, nullptr, nullptr, nullptr);
    // decoder: h1<-enc[2], h2<-enc[1], h3<-enc[0]
    gru_layer_kernel<TS, TGI, 0, true, false, false><<<grid, blk, 0, stream>>>(
        outputs, nullptr, nullptr, c1_Wih, c1_Whh, c1_bih, c1_bhh, enc + 120,
        ws0, nullptr, nullptr, nullptr, nullptr);
    gi_gemm_kernel<TS, TGI><<<ggrid, blk, 0, stream>>>(ws0, c2_Wih, c2_bih, gi);
    gru_layer_kernel<TS, TGI, 2, true, false, false><<<grid, blk, 0, stream>>>(
        nullptr, nullptr, gi, nullptr, c2_Whh, nullptr, c2_bhh, enc + 60,
        ws1, nullptr, nullptr, nullptr, nullptr);
    gi_gemm_kernel<TS, TGI><<<ggrid, blk, 0, stream>>>(ws1, c3_Wih, c3_bih, gi);
    gru_layer_kernel<TS, TGI, 2, false, false, true><<<grid, blk, 0, stream>>>(
        nullptr, nullptr, gi, nullptr, c3_Whh, nullptr, c3_bhh, enc + 0,
        nullptr, nullptr, pred, lin_W, lin_b);
  } else {
    // legacy fallback (no gi buffer space): fused MODE1 vec layers
    gru_layer_kernel<TS, TGI, 0, true, true, false><<<grid, blk, 0, stream>>>(
        inputs, nullptr, nullptr, eW_ih0, eW_hh0, eb_ih0, eb_hh0, nullptr,
        ws0, enc + 0, nullptr, nullptr, nullptr);
    gru_layer_kernel<TS, TGI, 1, true, true, false><<<grid, blk, 0, stream>>>(
        nullptr, ws0, nullptr, eW_ih1, eW_hh1, eb_ih1, eb_hh1, nullptr,
        ws1, enc + 60, nullptr, nullptr, nullptr);
    gru_layer_kernel<TS, TGI, 1, false, true, false><<<grid, blk, 0, stream>>>(
        nullptr, ws1, nullptr, eW_ih2, eW_hh2, eb_ih2, eb_hh2, nullptr,
        nullptr, enc + 120, nullptr, nullptr, nullptr);
    gru_layer_kernel<TS, TGI, 0, true, false, false><<<grid, blk, 0, stream>>>(
        outputs, nullptr, nullptr, c1_Wih, c1_Whh, c1_bih, c1_bhh, enc + 120,
        ws0, nullptr, nullptr, nullptr, nullptr);
    gru_layer_kernel<TS, TGI, 1, true, false, false><<<grid, blk, 0, stream>>>(
        nullptr, ws0, nullptr, c2_Wih, c2_Whh, c2_bih, c2_bhh, enc + 60,
        ws1, nullptr, nullptr, nullptr, nullptr);
    gru_layer_kernel<TS, TGI, 1, false, false, true><<<grid, blk, 0, stream>>>(
        nullptr, ws1, nullptr, c3_Wih, c3_Whh, c3_bih, c3_bhh, enc + 0,
        nullptr, nullptr, pred, lin_W, lin_b);
  }
}

}  // namespace

extern "C" void kernel_launch(void* const* d_in, const int* in_sizes, int n_in,
                              void* d_out, int out_size, void* d_ws, size_t ws_size,
                              hipStream_t stream) {
  const float* inputs  = (const float*)d_in[0];
  const float* outputs = (const float*)d_in[1];
  const float* eW_ih0 = (const float*)d_in[2];  const float* eW_hh0 = (const float*)d_in[3];
  const float* eb_ih0 = (const float*)d_in[4];  const float* eb_hh0 = (const float*)d_in[5];
  const float* eW_ih1 = (const float*)d_in[6];  const float* eW_hh1 = (const float*)d_in[7];
  const float* eb_ih1 = (const float*)d_in[8];  const float* eb_hh1 = (const float*)d_in[9];
  const float* eW_ih2 = (const float*)d_in[10]; const float* eW_hh2 = (const float*)d_in[11];
  const float* eb_ih2 = (const float*)d_in[12]; const float* eb_hh2 = (const float*)d_in[13];
  const float* c1_Wih = (const float*)d_in[14]; const float* c1_Whh = (const float*)d_in[15];
  const float* c1_bih = (const float*)d_in[16]; const float* c1_bhh = (const float*)d_in[17];
  const float* c2_Wih = (const float*)d_in[18]; const float* c2_Whh = (const float*)d_in[19];
  const float* c2_bih = (const float*)d_in[20]; const float* c2_bhh = (const float*)d_in[21];
  const float* c3_Wih = (const float*)d_in[22]; const float* c3_Whh = (const float*)d_in[23];
  const float* c3_bih = (const float*)d_in[24]; const float* c3_bhh = (const float*)d_in[25];
  const float* lin_W  = (const float*)d_in[26]; const float* lin_b  = (const float*)d_in[27];

  float* pred = (float*)d_out;                 // [B][T]
  float* enc  = pred + (size_t)B * T;          // [B][3][H]

  const size_t seq = (size_t)T * B * H;   // elements per ys buffer
  const size_t tbg = (size_t)T * B * G;   // elements in gi buffer

#define ARGS inputs, outputs, \
    eW_ih0, eW_hh0, eb_ih0, eb_hh0, eW_ih1, eW_hh1, eb_ih1, eb_hh1, \
    eW_ih2, eW_hh2, eb_ih2, eb_hh2, \
    c1_Wih, c1_Whh, c1_bih, c1_bhh, c2_Wih, c2_Whh, c2_bih, c2_bhh, \
    c3_Wih, c3_Whh, c3_bih, c3_bhh, lin_W, lin_b, pred, enc, d_ws, stream

  if (ws_size >= 2 * seq * sizeof(float) + tbg * sizeof(float)) {
    launch_all<float, float, true>(ARGS);                       // 629 MB
  } else if (ws_size >= 2 * seq * sizeof(__hip_bfloat16) + tbg * sizeof(float)) {
    launch_all<__hip_bfloat16, float, true>(ARGS);              // 503 MB
  } else if (ws_size >= 2 * seq * sizeof(__hip_bfloat16) + tbg * sizeof(__hip_bfloat16)) {
    launch_all<__hip_bfloat16, __hip_bfloat16, true>(ARGS);     // 314 MB
  } else if (ws_size >= 2 * seq * sizeof(float)) {
    launch_all<float, float, false>(ARGS);                      // 252 MB legacy
  } else {
    launch_all<__hip_bfloat16, float, false>(ARGS);             // 126 MB legacy
  }
#undef ARGS
}

// Round 5
// 3467.059 us; speedup vs baseline: 1.3905x; 1.3905x over previous
//
#include <hip/hip_runtime.h>
#include <hip/hip_bf16.h>

namespace {

constexpr int B = 1024, T = 512, H = 60, G = 180, NTHR = 192;
constexpr int TT = 8;        // time-tile: input-gemm batch depth
constexpr int NT = T / TT;   // 64 tiles

__device__ __forceinline__ float sigm(float x) { return 1.f / (1.f + __expf(-x)); }
__device__ __forceinline__ float tanh_fast(float x) {
  x = fminf(fmaxf(x, -15.f), 15.f);
  const float e = __expf(-2.f * x);
  return (1.f - e) / (1.f + e);
}

__device__ __forceinline__ float ldcvt(const float* p) { return *p; }
__device__ __forceinline__ float ldcvt(const __hip_bfloat16* p) { return __bfloat162float(*p); }
__device__ __forceinline__ void stcvt(float* p, float v) { *p = v; }
__device__ __forceinline__ void stcvt(__hip_bfloat16* p, float v) { *p = __float2bfloat16(v); }

// 4-way-split Whh·h accumulation (breaks the 60-deep dependent FMA chain)
#define ACCH(i, dst)                                                  \
  {                                                                   \
    const float4 hv = *(const float4*)&h_sh[(i) * 4];                 \
    dst = fmaf(Wh##i.x, hv.x, dst);                                   \
    dst = fmaf(Wh##i.y, hv.y, dst);                                   \
    dst = fmaf(Wh##i.z, hv.z, dst);                                   \
    dst = fmaf(Wh##i.w, hv.w, dst);                                   \
  }
#define ACCH_ALL                                                      \
  ACCH(0, c0) ACCH(1, c1) ACCH(2, c2) ACCH(3, c3)                     \
  ACCH(4, c0) ACCH(5, c1) ACCH(6, c2) ACCH(7, c3)                     \
  ACCH(8, c0) ACCH(9, c1) ACCH(10, c2) ACCH(11, c3)                   \
  ACCH(12, c0) ACCH(13, c1) ACCH(14, c2)

#define LWH_ALL                                                       \
  LWH(0) LWH(1) LWH(2) LWH(3) LWH(4) LWH(5) LWH(6) LWH(7)             \
  LWH(8) LWH(9) LWH(10) LWH(11) LWH(12) LWH(13) LWH(14)

// ---------------------------------------------------------------------------
// Scalar-input GRU layer (F=1). Proven shape: 60 weight floats/thread stay
// register-resident (62 us, no scratch traffic).
// ---------------------------------------------------------------------------
template <typename TS, bool WRITE_YS, bool WRITE_ENC>
__global__ __launch_bounds__(NTHR, 1) void gru_scalar_kernel(
    const float* __restrict__ xscalar,  // [B][T]
    const float* __restrict__ Wih,      // [180][1]
    const float* __restrict__ Whh,      // [180][60]
    const float* __restrict__ bih, const float* __restrict__ bhh,
    const float* __restrict__ h_init,   // nullptr => zeros; [b*180 + j]
    TS* __restrict__ ys_out,            // [T][B][H]
    float* __restrict__ enc_out)        // pre-offset by slot; [b*180 + j]
{
  const int tid = threadIdx.x;
  const int b = blockIdx.x;

  __shared__ __align__(16) float h_sh[64];
  __shared__ float Ar[60], Az[60], Nn[60], Hn[60];
  __shared__ float xs_seq[T];

  const int rr = (tid < G) ? tid : 0;

  float4 Wh0, Wh1, Wh2, Wh3, Wh4, Wh5, Wh6, Wh7, Wh8, Wh9, Wh10, Wh11, Wh12, Wh13, Wh14;
#define LWH(i) Wh##i = *(const float4*)&Whh[(size_t)rr * H + (i) * 4];
  LWH_ALL
#undef LWH
  const float wih0 = Wih[rr];
  const float bi = bih[rr];
  const float bh = bhh[rr];

  if (tid < H) h_sh[tid] = h_init ? h_init[(size_t)b * G + tid] : 0.f;
  for (int i = tid; i < T; i += NTHR) xs_seq[i] = xscalar[(size_t)b * T + i];
  __syncthreads();

  const int g = tid / H;
  const int j = tid - g * H;

  for (int t = 0; t < T; ++t) {
    if (tid < G) {
      float c0 = bh, c1 = 0.f, c2 = 0.f, c3 = 0.f;
      ACCH_ALL
      const float c = (c0 + c1) + (c2 + c3);
      const float a = fmaf(wih0, xs_seq[t], bi);
      if (g == 0)       Ar[j] = a + c;
      else if (g == 1)  Az[j] = a + c;
      else            { Nn[j] = a; Hn[j] = c; }
    }
    __syncthreads();

    if (tid < H) {
      const float rg = sigm(Ar[tid]);
      const float zg = sigm(Az[tid]);
      const float nv = tanh_fast(fmaf(rg, Hn[tid], Nn[tid]));
      const float hnew = fmaf(zg, h_sh[tid] - nv, nv);
      h_sh[tid] = hnew;
      if constexpr (WRITE_YS)
        stcvt(&ys_out[(size_t)t * B * H + (size_t)b * H + tid], hnew);
    }
    __syncthreads();
  }

  if constexpr (WRITE_ENC) {
    if (tid < H) enc_out[(size_t)b * G + tid] = h_sh[tid];
  }
}

// ---------------------------------------------------------------------------
// Vector-input GRU layer, time-tiled fused input-gemm:
//   per 8-step tile: (a) prefetch next x-tile to regs, (b) gemm phase --
//   re-load Wih row from L1/L2 (43 KB, shared across all 1024 blocks,
//   deliberately NOT register-resident: 120 wt floats/thread is past the
//   backend's spill threshold, see rounds 1-4's 91 GB scratch traffic) and
//   produce 8 steps of gi into LDS, (c) 8 recurrent steps with the proven
//   60-float register-resident Whh row.
// ---------------------------------------------------------------------------
template <typename TS, bool WRITE_YS, bool WRITE_ENC, bool WRITE_PRED>
__global__ __launch_bounds__(NTHR, 1) void gru_vec_kernel(
    const TS* __restrict__ xseq,        // [T][B][H]
    const float* __restrict__ Wih,      // [180][60]
    const float* __restrict__ Whh,      // [180][60]
    const float* __restrict__ bih, const float* __restrict__ bhh,
    const float* __restrict__ h_init,   // nullptr => zeros; [b*180 + j]
    TS* __restrict__ ys_out,            // [T][B][H]
    float* __restrict__ enc_out,        // pre-offset by slot; [b*180 + j]
    float* __restrict__ pred_out,       // [B][T]
    const float* __restrict__ lin_W,    // [60]
    const float* __restrict__ lin_b)    // [1]
{
  const int tid = threadIdx.x;
  const int b = blockIdx.x;

  __shared__ __align__(16) float h_sh[64];
  __shared__ __align__(16) float x_sh[2][TT * H];   // 2 x 480
  __shared__ float gi_sh[TT][G];                    // 8 x 180
  __shared__ float Ar[60], Az[60], Nn[60], Hn[60];
  __shared__ float pv[64];

  const int rr = (tid < G) ? tid : 0;

  float4 Wh0, Wh1, Wh2, Wh3, Wh4, Wh5, Wh6, Wh7, Wh8, Wh9, Wh10, Wh11, Wh12, Wh13, Wh14;
#define LWH(i) Wh##i = *(const float4*)&Whh[(size_t)rr * H + (i) * 4];
  LWH_ALL
#undef LWH
  const float bi = bih[rr];
  const float bh = bhh[rr];

  float linw = 0.f, linb = 0.f;
  if constexpr (WRITE_PRED) {
    linw = lin_W[tid < H ? tid : 0];
    linb = lin_b[0];
  }

  if (tid < H) h_sh[tid] = h_init ? h_init[(size_t)b * G + tid] : 0.f;

  // stage tile 0 (480 elements, 192 threads -> up to 3 each)
  {
    const int i0 = tid, i1 = tid + NTHR, i2 = tid + 2 * NTHR;
    {
      const int s = i0 / H, hh = i0 - s * H;
      x_sh[0][i0] = ldcvt(&xseq[((size_t)s * B + b) * H + hh]);
    }
    {
      const int s = i1 / H, hh = i1 - s * H;
      x_sh[0][i1] = ldcvt(&xseq[((size_t)s * B + b) * H + hh]);
    }
    if (i2 < TT * H) {
      const int s = i2 / H, hh = i2 - s * H;
      x_sh[0][i2] = ldcvt(&xseq[((size_t)s * B + b) * H + hh]);
    }
  }
  __syncthreads();

  const int g = tid / H;
  const int j = tid - g * H;

  for (int tile = 0; tile < NT; ++tile) {
    const int cur = tile & 1;

    // --- prefetch next tile's x into registers (hidden under gemm+rec) ---
    float xr0 = 0.f, xr1 = 0.f, xr2 = 0.f;
    const int i0 = tid, i1 = tid + NTHR, i2 = tid + 2 * NTHR;
    if (tile + 1 < NT) {
      const size_t tb = (size_t)(tile + 1) * TT;
      {
        const int s = i0 / H, hh = i0 - s * H;
        xr0 = ldcvt(&xseq[((tb + s) * B + b) * H + hh]);
      }
      {
        const int s = i1 / H, hh = i1 - s * H;
        xr1 = ldcvt(&xseq[((tb + s) * B + b) * H + hh]);
      }
      if (i2 < TT * H) {
        const int s = i2 / H, hh = i2 - s * H;
        xr2 = ldcvt(&xseq[((tb + s) * B + b) * H + hh]);
      }
    }

    // compiler barrier: keep the Wih loads inside the tile loop (re-served
    // from L1/L2 each tile) instead of hoisted into registers -> spill.
    asm volatile("" ::: "memory");

    // --- gemm phase: gi_sh[s][rr] = bi + Wih[rr] . x[tile*TT+s] ---
    if (tid < G) {
      float acc[TT];
#pragma unroll
      for (int s = 0; s < TT; ++s) acc[s] = bi;
#pragma unroll
      for (int k = 0; k < H / 4; ++k) {
        const float4 w = *(const float4*)&Wih[(size_t)rr * H + k * 4];
#pragma unroll
        for (int s = 0; s < TT; ++s) {
          const float4 xv = *(const float4*)&x_sh[cur][s * H + k * 4];
          acc[s] = fmaf(w.x, xv.x, acc[s]);
          acc[s] = fmaf(w.y, xv.y, acc[s]);
          acc[s] = fmaf(w.z, xv.z, acc[s]);
          acc[s] = fmaf(w.w, xv.w, acc[s]);
        }
      }
#pragma unroll
      for (int s = 0; s < TT; ++s) gi_sh[s][rr] = acc[s];
    }

    // --- write prefetched x into the other buffer ---
    if (tile + 1 < NT) {
      x_sh[cur ^ 1][i0] = xr0;
      x_sh[cur ^ 1][i1] = xr1;
      if (i2 < TT * H) x_sh[cur ^ 1][i2] = xr2;
    }
    __syncthreads();  // gi_sh + next x_sh ready

    // --- 8 recurrent steps ---
    for (int s = 0; s < TT; ++s) {
      const int t = tile * TT + s;
      if (tid < G) {
        float c0 = bh, c1 = 0.f, c2 = 0.f, c3 = 0.f;
        ACCH_ALL
        const float c = (c0 + c1) + (c2 + c3);
        const float a = gi_sh[s][rr];
        if (g == 0)       Ar[j] = a + c;
        else if (g == 1)  Az[j] = a + c;
        else            { Nn[j] = a; Hn[j] = c; }
      }
      __syncthreads();

      if (tid < H) {
        const float rg = sigm(Ar[tid]);
        const float zg = sigm(Az[tid]);
        const float nv = tanh_fast(fmaf(rg, Hn[tid], Nn[tid]));
        const float hnew = fmaf(zg, h_sh[tid] - nv, nv);
        h_sh[tid] = hnew;
        if constexpr (WRITE_YS)
          stcvt(&ys_out[(size_t)t * B * H + (size_t)b * H + tid], hnew);
        if constexpr (WRITE_PRED) pv[tid] = hnew * linw;
      }
      __syncthreads();

      if constexpr (WRITE_PRED) {
        if (tid < 64) {
          float v = (tid < H) ? pv[tid] : 0.f;
#pragma unroll
          for (int off = 32; off; off >>= 1) v += __shfl_xor(v, off);
          if (tid == 0) pred_out[(size_t)b * T + t] = v + linb;
        }
      }
    }
  }

  if constexpr (WRITE_ENC) {
    if (tid < H) enc_out[(size_t)b * G + tid] = h_sh[tid];
  }
}

template <typename TS>
void launch_all(const float* inputs, const float* outputs,
                const float* eW_ih0, const float* eW_hh0, const float* eb_ih0, const float* eb_hh0,
                const float* eW_ih1, const float* eW_hh1, const float* eb_ih1, const float* eb_hh1,
                const float* eW_ih2, const float* eW_hh2, const float* eb_ih2, const float* eb_hh2,
                const float* c1_Wih, const float* c1_Whh, const float* c1_bih, const float* c1_bhh,
                const float* c2_Wih, const float* c2_Whh, const float* c2_bih, const float* c2_bhh,
                const float* c3_Wih, const float* c3_Whh, const float* c3_bih, const float* c3_bhh,
                const float* lin_W, const float* lin_b,
                float* pred, float* enc, void* d_ws, hipStream_t stream) {
  const size_t seq = (size_t)T * B * H;
  TS* ws0 = (TS*)d_ws;
  TS* ws1 = ws0 + seq;
  const dim3 grid(B), blk(NTHR);

  // encoder
  gru_scalar_kernel<TS, true, true><<<grid, blk, 0, stream>>>(
      inputs, eW_ih0, eW_hh0, eb_ih0, eb_hh0, nullptr, ws0, enc + 0);
  gru_vec_kernel<TS, true, true, false><<<grid, blk, 0, stream>>>(
      ws0, eW_ih1, eW_hh1, eb_ih1, eb_hh1, nullptr,
      ws1, enc + 60, nullptr, nullptr, nullptr);
  gru_vec_kernel<TS, false, true, false><<<grid, blk, 0, stream>>>(
      ws1, eW_ih2, eW_hh2, eb_ih2, eb_hh2, nullptr,
      nullptr, enc + 120, nullptr, nullptr, nullptr);
  // decoder: h1<-enc[2], h2<-enc[1], h3<-enc[0]
  gru_scalar_kernel<TS, true, false><<<grid, blk, 0, stream>>>(
      outputs, c1_Wih, c1_Whh, c1_bih, c1_bhh, enc + 120, ws0, nullptr);
  gru_vec_kernel<TS, true, false, false><<<grid, blk, 0, stream>>>(
      ws0, c2_Wih, c2_Whh, c2_bih, c2_bhh, enc + 60,
      ws1, nullptr, nullptr, nullptr, nullptr);
  gru_vec_kernel<TS, false, false, true><<<grid, blk, 0, stream>>>(
      ws1, c3_Wih, c3_Whh, c3_bih, c3_bhh, enc + 0,
      nullptr, nullptr, pred, lin_W, lin_b);
}

}  // namespace

extern "C" void kernel_launch(void* const* d_in, const int* in_sizes, int n_in,
                              void* d_out, int out_size, void* d_ws, size_t ws_size,
                              hipStream_t stream) {
  const float* inputs  = (const float*)d_in[0];
  const float* outputs = (const float*)d_in[1];
  const float* eW_ih0 = (const float*)d_in[2];  const float* eW_hh0 = (const float*)d_in[3];
  const float* eb_ih0 = (const float*)d_in[4];  const float* eb_hh0 = (const float*)d_in[5];
  const float* eW_ih1 = (const float*)d_in[6];  const float* eW_hh1 = (const float*)d_in[7];
  const float* eb_ih1 = (const float*)d_in[8];  const float* eb_hh1 = (const float*)d_in[9];
  const float* eW_ih2 = (const float*)d_in[10]; const float* eW_hh2 = (const float*)d_in[11];
  const float* eb_ih2 = (const float*)d_in[12]; const float* eb_hh2 = (const float*)d_in[13];
  const float* c1_Wih = (const float*)d_in[14]; const float* c1_Whh = (const float*)d_in[15];
  const float* c1_bih = (const float*)d_in[16]; const float* c1_bhh = (const float*)d_in[17];
  const float* c2_Wih = (const float*)d_in[18]; const float* c2_Whh = (const float*)d_in[19];
  const float* c2_bih = (const float*)d_in[20]; const float* c2_bhh = (const float*)d_in[21];
  const float* c3_Wih = (const float*)d_in[22]; const float* c3_Whh = (const float*)d_in[23];
  const float* c3_bih = (const float*)d_in[24]; const float* c3_bhh = (const float*)d_in[25];
  const float* lin_W  = (const float*)d_in[26]; const float* lin_b  = (const float*)d_in[27];

  float* pred = (float*)d_out;                 // [B][T]
  float* enc  = pred + (size_t)B * T;          // [B][3][H]

  const size_t seq = (size_t)T * B * H;

#define ARGS inputs, outputs, \
    eW_ih0, eW_hh0, eb_ih0, eb_hh0, eW_ih1, eW_hh1, eb_ih1, eb_hh1, \
    eW_ih2, eW_hh2, eb_ih2, eb_hh2, \
    c1_Wih, c1_Whh, c1_bih, c1_bhh, c2_Wih, c2_Whh, c2_bih, c2_bhh, \
    c3_Wih, c3_Whh, c3_bih, c3_bhh, lin_W, lin_b, pred, enc, d_ws, stream

  if (ws_size >= 2 * seq * sizeof(float)) {
    launch_all<float>(ARGS);            // 252 MB (known to fit)
  } else {
    launch_all<__hip_bfloat16>(ARGS);   // 126 MB fallback
  }
#undef ARGS
}